// Round 5
// baseline (176.540 us; speedup 1.0000x reference)
//
#include <hip/hip_runtime.h>

#define KN 1000000
#define NCOLS 70400
#define SENTINEL -9999999.0f

// Order-preserving float<->uint encoding for atomicMax on floats, biased so
// that encode(SENTINEL) == 0 -> a zero-memset buffer decodes to SENTINEL.
__device__ __forceinline__ unsigned encodeF(float f) {
    unsigned b = __float_as_uint(f);
    return (b & 0x80000000u) ? ~b : (b | 0x80000000u);
}
__device__ __forceinline__ float decodeF(unsigned e) {
    unsigned b = (e & 0x80000000u) ? (e & 0x7fffffffu) : ~e;
    return __uint_as_float(b);
}
// encodeF(-9999999.0f): bits = 0xCB18967F -> ~ = 0x34E76980
#define ENC_SENT 0x34E76980u

#define RELU(x) fmaxf((x), 0.0f)

// ---- fully scalarized MLP: no arrays -> no alloca -> nothing can spill to
// ---- scratch (R1-R4 all ran ~90us because hidden state lived in scratch;
// ---- VGPR_Count=28 with occupancy 57% was the tell).

#define L1(j) const float h1_##j = RELU(fmaf(W1[4*(j)+0], x0, fmaf(W1[4*(j)+1], x1, \
                        fmaf(W1[4*(j)+2], x2, fmaf(W1[4*(j)+3], x3, b1[(j)])))));

#define DOT18(j) \
 fmaf(W2[(j)*18+ 0],h1_0 ,fmaf(W2[(j)*18+ 1],h1_1 ,fmaf(W2[(j)*18+ 2],h1_2 ,fmaf(W2[(j)*18+ 3],h1_3 , \
 fmaf(W2[(j)*18+ 4],h1_4 ,fmaf(W2[(j)*18+ 5],h1_5 ,fmaf(W2[(j)*18+ 6],h1_6 ,fmaf(W2[(j)*18+ 7],h1_7 , \
 fmaf(W2[(j)*18+ 8],h1_8 ,fmaf(W2[(j)*18+ 9],h1_9 ,fmaf(W2[(j)*18+10],h1_10,fmaf(W2[(j)*18+11],h1_11, \
 fmaf(W2[(j)*18+12],h1_12,fmaf(W2[(j)*18+13],h1_13,fmaf(W2[(j)*18+14],h1_14,fmaf(W2[(j)*18+15],h1_15, \
 fmaf(W2[(j)*18+16],h1_16,fmaf(W2[(j)*18+17],h1_17, b2[(j)]))))))))))))))))))

#define L2(j) const float h2_##j = RELU(DOT18(j));

#define DOT36(j) \
 fmaf(W3[(j)*36+ 0],h2_0 ,fmaf(W3[(j)*36+ 1],h2_1 ,fmaf(W3[(j)*36+ 2],h2_2 ,fmaf(W3[(j)*36+ 3],h2_3 , \
 fmaf(W3[(j)*36+ 4],h2_4 ,fmaf(W3[(j)*36+ 5],h2_5 ,fmaf(W3[(j)*36+ 6],h2_6 ,fmaf(W3[(j)*36+ 7],h2_7 , \
 fmaf(W3[(j)*36+ 8],h2_8 ,fmaf(W3[(j)*36+ 9],h2_9 ,fmaf(W3[(j)*36+10],h2_10,fmaf(W3[(j)*36+11],h2_11, \
 fmaf(W3[(j)*36+12],h2_12,fmaf(W3[(j)*36+13],h2_13,fmaf(W3[(j)*36+14],h2_14,fmaf(W3[(j)*36+15],h2_15, \
 fmaf(W3[(j)*36+16],h2_16,fmaf(W3[(j)*36+17],h2_17,fmaf(W3[(j)*36+18],h2_18,fmaf(W3[(j)*36+19],h2_19, \
 fmaf(W3[(j)*36+20],h2_20,fmaf(W3[(j)*36+21],h2_21,fmaf(W3[(j)*36+22],h2_22,fmaf(W3[(j)*36+23],h2_23, \
 fmaf(W3[(j)*36+24],h2_24,fmaf(W3[(j)*36+25],h2_25,fmaf(W3[(j)*36+26],h2_26,fmaf(W3[(j)*36+27],h2_27, \
 fmaf(W3[(j)*36+28],h2_28,fmaf(W3[(j)*36+29],h2_29,fmaf(W3[(j)*36+30],h2_30,fmaf(W3[(j)*36+31],h2_31, \
 fmaf(W3[(j)*36+32],h2_32,fmaf(W3[(j)*36+33],h2_33,fmaf(W3[(j)*36+34],h2_34,fmaf(W3[(j)*36+35],h2_35, \
 b3[(j)]))))))))))))))))))))))))))))))))))))

#define L34(j) v = fmaf(W4[(j)], RELU(DOT36(j)), v);

__global__ __launch_bounds__(256, 4) void mlp_scatter_kernel(
    const float* __restrict__ x,      // (4, K) : input_1[0,:,0,:]
    const int*   __restrict__ tidx,   // (K, 2) int32 pairs (row, col)
    const float* __restrict__ W1, const float* __restrict__ b1,   // (18,4)
    const float* __restrict__ W2, const float* __restrict__ b2,   // (36,18)
    const float* __restrict__ W3, const float* __restrict__ b3,   // (36,36)
    const float* __restrict__ W4, const float* __restrict__ b4,   // (1,36)
    unsigned* __restrict__ outU)
{
    const int k = blockIdx.x * blockDim.x + threadIdx.x;
    if (k >= KN) return;

    const float x0 = x[0 * KN + k];
    const float x1 = x[1 * KN + k];
    const float x2 = x[2 * KN + k];
    const float x3 = x[3 * KN + k];

    L1(0)  L1(1)  L1(2)  L1(3)  L1(4)  L1(5)  L1(6)  L1(7)  L1(8)
    L1(9)  L1(10) L1(11) L1(12) L1(13) L1(14) L1(15) L1(16) L1(17)

    L2(0)  L2(1)  L2(2)  L2(3)  L2(4)  L2(5)  L2(6)  L2(7)  L2(8)
    L2(9)  L2(10) L2(11) L2(12) L2(13) L2(14) L2(15) L2(16) L2(17)
    L2(18) L2(19) L2(20) L2(21) L2(22) L2(23) L2(24) L2(25) L2(26)
    L2(27) L2(28) L2(29) L2(30) L2(31) L2(32) L2(33) L2(34) L2(35)

    float v = b4[0];
    L34(0)  L34(1)  L34(2)  L34(3)  L34(4)  L34(5)  L34(6)  L34(7)  L34(8)
    L34(9)  L34(10) L34(11) L34(12) L34(13) L34(14) L34(15) L34(16) L34(17)
    L34(18) L34(19) L34(20) L34(21) L34(22) L34(23) L34(24) L34(25) L34(26)
    L34(27) L34(28) L34(29) L34(30) L34(31) L34(32) L34(33) L34(34) L34(35)

    // scatter-max on columns (row index irrelevant after the final row-max).
    // check-then-atomic: any cached value was genuinely written earlier in
    // this launch (buffer memset to 0 = enc(SENTINEL), monotone increasing),
    // so skipping when enc <= cur is always safe and cuts atomic traffic.
    const int col = ((const int2*)tidx)[k].y;
    const unsigned enc = encodeF(v) - ENC_SENT;
    const unsigned cur = outU[col];
    if (enc > cur) atomicMax(&outU[col], enc);
}

__global__ __launch_bounds__(256) void decode_kernel(unsigned* __restrict__ outU,
                                                     float* __restrict__ outF,
                                                     int out_size) {
    int gid = blockIdx.x * blockDim.x + threadIdx.x;
    if (gid < NCOLS) {
        outF[gid] = decodeF(outU[gid] + ENC_SENT);
    } else if (gid == NCOLS && out_size > NCOLS) {
        outF[gid] = 1.0f;  // flag
    }
}

extern "C" void kernel_launch(void* const* d_in, const int* in_sizes, int n_in,
                              void* d_out, int out_size, void* d_ws, size_t ws_size,
                              hipStream_t stream) {
    const float* input_1 = (const float*)d_in[0];   // (1,4,1,K)
    const int*   tidx    = (const int*)d_in[1];     // (K,2)
    const float* W1 = (const float*)d_in[2];
    const float* b1 = (const float*)d_in[3];
    const float* W2 = (const float*)d_in[4];
    const float* b2 = (const float*)d_in[5];
    const float* W3 = (const float*)d_in[6];
    const float* b3 = (const float*)d_in[7];
    const float* W4 = (const float*)d_in[8];
    const float* b4 = (const float*)d_in[9];

    unsigned* outU = (unsigned*)d_out;
    float*    outF = (float*)d_out;

    // Zero-init: biased encoding makes 0 decode to SENTINEL.
    hipMemsetAsync(outU, 0, (size_t)NCOLS * sizeof(unsigned), stream);

    mlp_scatter_kernel<<<(KN + 255) / 256, 256, 0, stream>>>(
        input_1, tidx, W1, b1, W2, b2, W3, b3, W4, b4, outU);

    decode_kernel<<<(out_size + 255) / 256, 256, 0, stream>>>(outU, outF, out_size);
}